// Round 1
// baseline (417.881 us; speedup 1.0000x reference)
//
#include <hip/hip_runtime.h>

#define HH 64
#define VV 50257
#define BB 32
#define LL 4096

constexpr float LN_EPS_F = 1e-5f;
constexpr float DELTA_EPS_F = 1e-6f;

// ---------------- DPP wave reduction (sum of 64 lanes -> lane 63) ----------------
template <int CTRL>
__device__ __forceinline__ float dpp_add(float x) {
  int t = __builtin_amdgcn_update_dpp(0, __float_as_int(x), CTRL, 0xF, 0xF, true);
  return x + __int_as_float(t);
}

__device__ __forceinline__ float wave_sum_lane63(float x) {
  x = dpp_add<0x111>(x);  // row_shr:1
  x = dpp_add<0x112>(x);  // row_shr:2
  x = dpp_add<0x114>(x);  // row_shr:4
  x = dpp_add<0x118>(x);  // row_shr:8
  x = dpp_add<0x142>(x);  // row_bcast:15
  x = dpp_add<0x143>(x);  // row_bcast:31
  return x;               // lane 63 holds the full sum
}

__device__ __forceinline__ float readlane_f(float x, int lane) {
  return __int_as_float(__builtin_amdgcn_readlane(__float_as_int(x), lane));
}

// ---------------- Kernel 1: encoder (embed gather + MLP + residual + LN + beta) ----
// one thread per token; weights in LDS (w1 transposed for vectorized reads)
__global__ __launch_bounds__(256, 2) void encoder_kernel(
    const int* __restrict__ seq, const float* __restrict__ embed,
    const float* __restrict__ w1, const float* __restrict__ b1,
    const float* __restrict__ w2, const float* __restrict__ b2,
    const float* __restrict__ ln_g, const float* __restrict__ ln_b,
    float* __restrict__ h_all, float* __restrict__ beta) {
  __shared__ float w1T[2 * HH][HH];  // [j][h]  (transposed w1)
  __shared__ float w2s[2 * HH][HH];  // [j][h]
  __shared__ float b1s[2 * HH];
  __shared__ float b2s[HH];
  __shared__ float gs[HH], bs[HH];

  int tid = threadIdx.x;
  for (int i = tid; i < 2 * HH * HH; i += 256) {
    int h = i >> 7, j = i & 127;
    w1T[j][h] = w1[i];
    w2s[i >> 6][i & 63] = w2[i];
  }
  if (tid < 2 * HH) b1s[tid] = b1[tid];
  if (tid < HH) { b2s[tid] = b2[tid]; gs[tid] = ln_g[tid]; bs[tid] = ln_b[tid]; }
  __syncthreads();

  int n = blockIdx.x * 256 + tid;  // token index in [0, B*L)
  int s = seq[n];
  const float4* ep = reinterpret_cast<const float4*>(embed + (size_t)s * HH);
  float4 e4[16];
#pragma unroll
  for (int i = 0; i < 16; ++i) e4[i] = ep[i];

  float4 a4[16];
#pragma unroll
  for (int i = 0; i < 16; ++i) {
    a4[i].x = b2s[4 * i + 0]; a4[i].y = b2s[4 * i + 1];
    a4[i].z = b2s[4 * i + 2]; a4[i].w = b2s[4 * i + 3];
  }

#pragma unroll 2
  for (int jj = 0; jj < 2 * HH; ++jj) {
    const float4* w1p = reinterpret_cast<const float4*>(w1T[jj]);
    float hj = b1s[jj];
#pragma unroll
    for (int i = 0; i < 16; ++i) {
      float4 w = w1p[i];
      hj = fmaf(e4[i].x, w.x, hj); hj = fmaf(e4[i].y, w.y, hj);
      hj = fmaf(e4[i].z, w.z, hj); hj = fmaf(e4[i].w, w.w, hj);
    }
    hj = fmaxf(hj, 0.f);
    const float4* w2p = reinterpret_cast<const float4*>(w2s[jj]);
#pragma unroll
    for (int i = 0; i < 16; ++i) {
      float4 w = w2p[i];
      a4[i].x = fmaf(hj, w.x, a4[i].x); a4[i].y = fmaf(hj, w.y, a4[i].y);
      a4[i].z = fmaf(hj, w.z, a4[i].z); a4[i].w = fmaf(hj, w.w, a4[i].w);
    }
  }

  // x = e + f ; LayerNorm
  float sum = 0.f;
#pragma unroll
  for (int i = 0; i < 16; ++i) {
    a4[i].x += e4[i].x; a4[i].y += e4[i].y; a4[i].z += e4[i].z; a4[i].w += e4[i].w;
    sum += (a4[i].x + a4[i].y) + (a4[i].z + a4[i].w);
  }
  float mu = sum * (1.f / HH);
  float vs = 0.f;
#pragma unroll
  for (int i = 0; i < 16; ++i) {
    float dx;
    dx = a4[i].x - mu; vs = fmaf(dx, dx, vs);
    dx = a4[i].y - mu; vs = fmaf(dx, dx, vs);
    dx = a4[i].z - mu; vs = fmaf(dx, dx, vs);
    dx = a4[i].w - mu; vs = fmaf(dx, dx, vs);
  }
  float rstd = rsqrtf(vs * (1.f / HH) + LN_EPS_F);

  float ss = 0.f;
  float4* hp = reinterpret_cast<float4*>(h_all + (size_t)n * HH);
#pragma unroll
  for (int i = 0; i < 16; ++i) {
    float4 o;
    o.x = fmaf((a4[i].x - mu) * rstd, gs[4 * i + 0], bs[4 * i + 0]);
    o.y = fmaf((a4[i].y - mu) * rstd, gs[4 * i + 1], bs[4 * i + 1]);
    o.z = fmaf((a4[i].z - mu) * rstd, gs[4 * i + 2], bs[4 * i + 2]);
    o.w = fmaf((a4[i].w - mu) * rstd, gs[4 * i + 3], bs[4 * i + 3]);
    ss = fmaf(o.x, o.x, ss); ss = fmaf(o.y, o.y, ss);
    ss = fmaf(o.z, o.z, ss); ss = fmaf(o.w, o.w, ss);
    hp[i] = o;
  }
  beta[n] = 1.f / (ss + DELTA_EPS_F);  // beta_t = 1/(k.k + eps)
}

// ---------------- Kernel 2: backward delta scan (one wave per batch) ----------------
// r = sum_t k_t (k_t . P_t),  P_T = q,  P_{t-1} = P_t - beta_t (k_t.P_t) k_t
// then y = r @ rp_w + rp_b
constexpr int GS = 32;        // prefetch group size
constexpr int NG = LL / GS;   // 128 groups; slot t = L-1 = 4095 is zeroed (skipped)

__device__ __forceinline__ void delta_group(const float (&kk)[GS], float bv,
                                            float& P, float& r) {
#pragma unroll
  for (int i = GS - 1; i >= 0; --i) {
    float k = kk[i];
    float bt = readlane_f(bv, i);        // beta_{base+i}, off critical path
    float m = k * P;
    float s = wave_sum_lane63(m);
    float d = readlane_f(s, 63);         // k_t . P_t (uniform)
    r = fmaf(d, k, r);
    P = fmaf(-(bt * d), k, P);
  }
}

__global__ __launch_bounds__(64) void scan_kernel(
    const float* __restrict__ h_all, const float* __restrict__ beta,
    const int* __restrict__ read_pos_p,
    const float* __restrict__ rp_w, const float* __restrict__ rp_b,
    float* __restrict__ yv) {
  int b = blockIdx.x, j = threadIdx.x;
  const float* hb = h_all + (size_t)b * LL * HH;
  const float* betab = beta + (size_t)b * LL;
  int rpv = read_pos_p[0];
  int pos = rpv < 0 ? rpv + LL : rpv;

  float P = hb[(size_t)pos * HH + j];
  float r = 0.f;

  float ka[GS], kb_[GS];
  float bva = 0.f, bvb = 0.f;

  {  // load group NG-1 (t = 4064..4095); zero slot for t=4095 (not a key)
    const float* gp = hb + (size_t)(NG - 1) * GS * HH + j;
#pragma unroll
    for (int i = 0; i < GS; ++i) ka[i] = gp[i * HH];
    bva = betab[(NG - 1) * GS + (j & (GS - 1))];
    ka[GS - 1] = 0.f;
  }

#pragma unroll 1
  for (int g = NG - 1; g >= 1; g -= 2) {
    {  // prefetch group g-1
      const float* gp = hb + (size_t)(g - 1) * GS * HH + j;
#pragma unroll
      for (int i = 0; i < GS; ++i) kb_[i] = gp[i * HH];
      bvb = betab[(g - 1) * GS + (j & (GS - 1))];
    }
    delta_group(ka, bva, P, r);
    if (g > 1) {  // prefetch group g-2
      const float* gp = hb + (size_t)(g - 2) * GS * HH + j;
#pragma unroll
      for (int i = 0; i < GS; ++i) ka[i] = gp[i * HH];
      bva = betab[(g - 2) * GS + (j & (GS - 1))];
    }
    delta_group(kb_, bvb, P, r);
  }

  // y = r @ rp_w + rp_b  (rp_w is [H][H], lane j computes column j)
  __shared__ float rs[HH];
  rs[j] = r;
  __syncthreads();
  float yj = rp_b[j];
#pragma unroll 8
  for (int h = 0; h < HH; ++h) yj = fmaf(rs[h], rp_w[h * HH + j], yj);
  yv[b * HH + j] = yj;
}

// ---------------- Kernel 3: output GEMM  out[b][v] = y[b] . out_w[:,v] + out_b[v] ---
__global__ __launch_bounds__(256) void out_kernel(
    const float* __restrict__ yv, const float* __restrict__ out_w,
    const float* __restrict__ out_b, float* __restrict__ out) {
  __shared__ float ys[BB * HH];
  for (int i = threadIdx.x; i < BB * HH; i += 256) ys[i] = yv[i];
  __syncthreads();

  int v = blockIdx.x * 256 + threadIdx.x;
  if (v >= VV) return;

  float acc[BB];
  float ob = out_b[v];
#pragma unroll
  for (int b = 0; b < BB; ++b) acc[b] = ob;

  for (int h = 0; h < HH; ++h) {
    float w = out_w[(size_t)h * VV + v];
#pragma unroll
    for (int b = 0; b < BB; ++b) acc[b] = fmaf(ys[b * HH + h], w, acc[b]);
  }
#pragma unroll
  for (int b = 0; b < BB; ++b) out[(size_t)b * VV + v] = acc[b];
}

// ---------------- launch ----------------
extern "C" void kernel_launch(void* const* d_in, const int* in_sizes, int n_in,
                              void* d_out, int out_size, void* d_ws, size_t ws_size,
                              hipStream_t stream) {
  (void)in_sizes; (void)n_in; (void)out_size; (void)ws_size;
  const int*   seq   = (const int*)d_in[0];
  const int*   rp    = (const int*)d_in[1];
  const float* embed = (const float*)d_in[2];
  const float* w1    = (const float*)d_in[3];
  const float* b1    = (const float*)d_in[4];
  const float* w2    = (const float*)d_in[5];
  const float* b2    = (const float*)d_in[6];
  const float* ln_g  = (const float*)d_in[7];
  const float* ln_b  = (const float*)d_in[8];
  const float* rp_w  = (const float*)d_in[9];
  const float* rp_b  = (const float*)d_in[10];
  const float* out_w = (const float*)d_in[11];
  const float* out_b = (const float*)d_in[12];
  float* out = (float*)d_out;

  // workspace layout (~34.1 MB): h_all | beta | y
  float* h_all = (float*)d_ws;
  float* beta  = h_all + (size_t)BB * LL * HH;
  float* yv    = beta + (size_t)BB * LL;

  encoder_kernel<<<BB * LL / 256, 256, 0, stream>>>(seq, embed, w1, b1, w2, b2,
                                                    ln_g, ln_b, h_all, beta);
  scan_kernel<<<BB, 64, 0, stream>>>(h_all, beta, rp, rp_w, rp_b, yv);
  out_kernel<<<(VV + 255) / 256, 256, 0, stream>>>(yv, out_w, out_b, out);
}